// Round 13
// baseline (137.727 us; speedup 1.0000x reference)
//
#include <hip/hip_runtime.h>

// Correlation via bf16 MFMA banded Gram.
// out[b, dyp*21+k, y, x] = (1/256) * sum_c in1[b,c,y,x] * in2[b,c,y+2(dyp-10), x+2(k-10)]
// Layouts (workspace): Ag/Bg[b*64+y][par*48+col][c] bf16, x = 2*col+par.
//
// R19: break the 16-waves/CU ceiling. Evidence: only TLP has ever moved main
// (R13->R15: 12->16 waves/CU = 59.7->42.6us, ~proportional); barriers (R9) and
// A-load ILP (R18 asm pipeline, correct vmcnt math) both falsified. LDS 56.8KB
// capped us at 2 blocks/CU. New: each block does ONE p-round (grid 1536 =
// p(3) x par(2) x b(4) x y2(64), 8 waves, dyp = p*8+slot) and the output is
// emitted in TWO k-passes (k in [0,11) then [11,21)) so scr = [8][528] =
// 16.9KB. LDS = 24,576 + 16,896 = 41,472B -> 3 blocks/CU = 24 waves/CU.
// B-half restaged 3x, but per-XCD B set = 1.57MB -> L2-resident restage.
// Chunk = (b,yhi) w/ par in dispatch bit0 (R18 store-merge). Asm pipe dropped.
// Harness fact: 2x ~43us fillBufferAligned (256MiB ws poison) = fixed floor.

typedef short bf16x8 __attribute__((ext_vector_type(8)));
typedef float f32x4  __attribute__((ext_vector_type(4)));

#define PLANE 24576         // shorts per (b,y) plane: 96 rows * 256 c
#define ST    40            // prepass LDS row stride (shorts)

__device__ __forceinline__ short f2bf(float f) {
    union { float f; unsigned u; } x; x.f = f;
    const unsigned u = x.u;
    return (short)((u + 0x7fffu + ((u >> 16) & 1u)) >> 16);
}

// ---------- prepass: fp32 [b][c][y][x] -> bf16 [b*64+y][par*48+col][c] ----------
// block = (sel, b, ytile of 8, ctile of 32ch). Reads 3KB contiguous per channel.
__global__ __launch_bounds__(512)
void corr_prepass(const float* __restrict__ in1, const float* __restrict__ in2,
                  short* __restrict__ dstA, short* __restrict__ dstB) {
    const int bid = blockIdx.x;
    const int sel = bid >> 8;
    const int r   = bid & 255;
    const int b   = r >> 6;
    const int yt  = (r >> 3) & 7;
    const int ct  = r & 7;
    const int c0 = ct * 32, y0 = yt * 8;
    const float* src = sel ? in2 : in1;
    short* dst = sel ? dstB : dstA;

    __shared__ __align__(16) short T[768 * ST];   // [xx = yy*96+x][32c], 61.4 KB
    const int tid = threadIdx.x;

#pragma unroll
    for (int it = 0; it < 2; ++it) {
        const int d = it * 512 + tid;            // [0,1024), use d<768
        if (d < 768) {
            const int g = d / 192;               // channel octet 0..3
            const int f = d - g * 192;           // float4 index in 8y*96x chunk
            float4 v[8];
#pragma unroll
            for (int j = 0; j < 8; ++j) {
                const int c = c0 + g * 8 + j;
                v[j] = *(const float4*)(src + ((size_t)(b * 256 + c) * 64 + y0) * 96 + 4 * f);
            }
            bf16x8 w0, w1, w2, w3;
#pragma unroll
            for (int j = 0; j < 8; ++j) {
                w0[j] = f2bf(v[j].x); w1[j] = f2bf(v[j].y);
                w2[j] = f2bf(v[j].z); w3[j] = f2bf(v[j].w);
            }
            const int perm = ((g ^ (f & 3)) * 8);
            const int base = 4 * f * ST + perm;
            *(bf16x8*)&T[base]          = w0;
            *(bf16x8*)&T[base + ST]     = w1;
            *(bf16x8*)&T[base + 2*ST]   = w2;
            *(bf16x8*)&T[base + 3*ST]   = w3;
        }
    }
    __syncthreads();

#pragma unroll
    for (int it = 0; it < 6; ++it) {
        const int D  = it * 512 + tid;           // [0,3072)
        const int Rl = D >> 2, gp = D & 3;
        const int yy  = Rl / 96;
        const int rl  = Rl - yy * 96;
        const int par = rl / 48;
        const int col = rl - par * 48;
        const int x   = 2 * col + par;
        const int xx  = yy * 96 + x;
        const int perm = ((gp ^ ((xx >> 2) & 3)) * 8);
        const bf16x8 w = *(const bf16x8*)&T[xx * ST + perm];
        const size_t Rg = (size_t)(b * 64 + y0 + yy) * 96 + par * 48 + col;
        *(bf16x8*)(dst + Rg * 256 + c0 + gp * 8) = w;
    }
}

// ---------- main kernel: 512 thr = 8 waves = 8 slots; ONE p-round per block ----------
__global__ __launch_bounds__(512, 3)
void corr_mfma(const short* __restrict__ Ag, const short* __restrict__ Bg,
               float* __restrict__ out) {
    // grid 1536 = 8 XCD-chunks x 192. chunk = (b, y2-half); inner = (p, y2lo, par)
    // with par in dispatch bit0 so par-siblings are launch-adjacent (L2 write merge).
    const int bhw = blockIdx.x;                  // [0,1536)
    const int xcd = bhw & 7;
    const int i   = bhw >> 3;                    // [0,192)
    const int b   = xcd >> 1;
    const int yhi = xcd & 1;
    const int p   = i >> 6;                      // [0,3)
    const int rem = i & 63;
    const int par = rem & 1;
    const int y2  = (yhi << 5) | (rem >> 1);
    const int by2 = b * 64 + y2;

    const int tid  = threadIdx.x;
    const int lane = tid & 63, slot = tid >> 6;  // slot in [0,8)
    const int n    = lane & 15, q = lane >> 4;

    __shared__ __align__(16) short Bsh[48 * 256];    // 24576 B, XOR-swizzled rows
    __shared__ __align__(16) float scr[8][528];      // 16896 B, per-wave, 2 k-passes

    // stage B(b,y2) par-half ONCE (swizzle: short_idx ^= (row&7)<<3)
    {
        const short* src = Bg + (size_t)by2 * PLANE + par * 48 * 256;
#pragma unroll
        for (int it = 0; it < 3; ++it) {
            const int j   = it * 512 + tid;      // [0,1536)
            const int row = j >> 5;              // [0,48)
            const int ofs = (row * 256 + (j & 31) * 8) ^ ((row & 7) << 3);
            *(bf16x8*)&Bsh[ofs] = *(const bf16x8*)(src + j * 8);
        }
    }
    __syncthreads();                             // the ONLY block-wide barrier

    const int dyp = p * 8 + slot;
    const int y   = y2 + 20 - 2 * dyp;
    if (dyp >= 21 || y < 0 || y >= 64) return;   // dead wave frees its SIMD slot

    const bool v0 = (n >= 10), v3 = (n < 10);
    const int r0 = v0 ? (n - 10) : 0;
    const int r1 = n + 6;
    const int r2 = n + 22;
    const int r3 = v3 ? (n + 38) : 0;            // all in [0,48)

    float* const sc = scr[slot];

    f32x4 acc[9];
#pragma unroll
    for (int t2 = 0; t2 < 9; ++t2) acc[t2] = (f32x4)0.0f;

    // Per-lane A base; (Xi,ks) offset = Xi*4096 + ks*32 shorts.
    const short* Ap = Ag + ((size_t)(b * 64 + y) * 96 + par * 48) * 256
                    + n * 256 + q * 8;

    // 4-deep rotating ks-step buffers (compiler-scheduled; ILP proven non-limiting).
    bf16x8 a0[3], a1[3], a2[3], a3[3];
#define LOADA(buf, ks) \
    buf[0] = *(const bf16x8*)(Ap + 0 * 4096 + (ks) * 32); \
    buf[1] = *(const bf16x8*)(Ap + 1 * 4096 + (ks) * 32); \
    buf[2] = *(const bf16x8*)(Ap + 2 * 4096 + (ks) * 32);

    LOADA(a0, 0) LOADA(a1, 1) LOADA(a2, 2) LOADA(a3, 3)

#define STEP(ks, ab, PF) { \
    const int ko = (ks) * 32 + q * 8; \
    bf16x8 b0 = *(const bf16x8*)&Bsh[(r0 * 256 + ko) ^ ((r0 & 7) << 3)]; if (!v0) b0 = 0; \
    bf16x8 b1 = *(const bf16x8*)&Bsh[(r1 * 256 + ko) ^ ((r1 & 7) << 3)]; \
    bf16x8 b2 = *(const bf16x8*)&Bsh[(r2 * 256 + ko) ^ ((r2 & 7) << 3)]; \
    bf16x8 b3 = *(const bf16x8*)&Bsh[(r3 * 256 + ko) ^ ((r3 & 7) << 3)]; if (!v3) b3 = 0; \
    acc[0] = __builtin_amdgcn_mfma_f32_16x16x32_bf16(ab[0], b0, acc[0], 0, 0, 0); \
    acc[1] = __builtin_amdgcn_mfma_f32_16x16x32_bf16(ab[0], b1, acc[1], 0, 0, 0); \
    acc[2] = __builtin_amdgcn_mfma_f32_16x16x32_bf16(ab[0], b2, acc[2], 0, 0, 0); \
    acc[3] = __builtin_amdgcn_mfma_f32_16x16x32_bf16(ab[1], b1, acc[3], 0, 0, 0); \
    acc[4] = __builtin_amdgcn_mfma_f32_16x16x32_bf16(ab[1], b2, acc[4], 0, 0, 0); \
    acc[5] = __builtin_amdgcn_mfma_f32_16x16x32_bf16(ab[1], b3, acc[5], 0, 0, 0); \
    acc[6] = __builtin_amdgcn_mfma_f32_16x16x32_bf16(ab[2], b2, acc[6], 0, 0, 0); \
    acc[7] = __builtin_amdgcn_mfma_f32_16x16x32_bf16(ab[2], b3, acc[7], 0, 0, 0); \
    if (PF) { LOADA(ab, (ks) + 4) } \
}
    // acc[8] = (X2,U4): most B cols OOB; its in-band (k,xe) outputs are true zeros.

    STEP(0, a0, 1) STEP(1, a1, 1) STEP(2, a2, 1) STEP(3, a3, 1)
    STEP(4, a0, 0) STEP(5, a1, 0) STEP(6, a2, 0) STEP(7, a3, 0)
#undef STEP
#undef LOADA

    // Two k-passes: scatter acc subset into sc[xe*11 + (k-k0)], then store.
    const int mb = q * 4;
#pragma unroll
    for (int kp = 0; kp < 2; ++kp) {
        const int k0 = kp ? 11 : 0;
        const int kn = kp ? 10 : 11;

#pragma unroll
        for (int t2 = 0; t2 < 9; ++t2) {
            const int Xi = (t2 < 3) ? 0 : (t2 < 6 ? 1 : 2);
            constexpr int UJ[9] = {0, 1, 2, 1, 2, 3, 2, 3, 4};
            const int ub = UJ[t2] * 16;
#pragma unroll
            for (int rr = 0; rr < 4; ++rr) {
                const int xe = Xi * 16 + mb + rr;
                const int k  = ub + n - xe;
                if ((unsigned)(k - k0) < (unsigned)kn)
                    sc[xe * 11 + (k - k0)] = acc[t2][rr];
            }
        }

        // store this k-pass: k-major, x stride-2 (par sibling fills other half)
        const size_t obase = ((size_t)(b * 441 + dyp * 21 + k0) * 64 + y) * 96 + par;
        const int nit = kp ? 8 : 9;              // ceil(kn*48 / 64)
#pragma unroll
        for (int it = 0; it < 9; ++it) {
            if (it < nit) {
                const int e = it * 64 + lane;
                if (e < kn * 48) {
                    const int k  = e / 48;
                    const int xe = e - k * 48;
                    out[obase + (size_t)k * 6144 + 2 * xe] = sc[xe * 11 + k] * (1.0f / 256.0f);
                }
            }
        }
    }
}

extern "C" void kernel_launch(void* const* d_in, const int* in_sizes, int n_in,
                              void* d_out, int out_size, void* d_ws, size_t ws_size,
                              hipStream_t stream) {
    const float* in1 = (const float*)d_in[0];
    const float* in2 = (const float*)d_in[1];
    float* out = (float*)d_out;

    short* Ag = (short*)d_ws;                    // 256 planes * 24576 shorts = 12.58 MB
    short* Bg = Ag + (size_t)256 * PLANE;        // 12.58 MB

    corr_prepass<<<dim3(512), dim3(512), 0, stream>>>(in1, in2, Ag, Bg);
    corr_mfma<<<dim3(1536), dim3(512), 0, stream>>>(Ag, Bg, out);
}